// Round 8
// baseline (4192.166 us; speedup 1.0000x reference)
//
#include <hip/hip_runtime.h>
#include <math.h>

// ---------------------------------------------------------------------------
// HybridBlock: rmsnorm -> LiquidCell scan -> PLIF scan -> sparse synapse +
// sigmoid gate (residual) -> rmsnorm -> SwiGLU-style FFN (residual).
// B=4, T=1024, D=1024, H=8192.
// ---------------------------------------------------------------------------

#define Bsz 4
#define Tsz 1024
#define Dsz 1024
#define Hsz 8192
#define JCUT 24                 // workers handle t-chunks j<24; post-kernels the rest
#define MAGICC 0x5EEDC0DEu

typedef __attribute__((ext_vector_type(8))) short short8;
typedef __attribute__((ext_vector_type(4))) float floatx4_t;

// ---- helpers --------------------------------------------------------------

__device__ __forceinline__ unsigned short f2bf(float f) {
  union { float f; unsigned u; } c; c.f = f;
  unsigned x = c.u;
  unsigned r = (x + 0x7FFFu + ((x >> 16) & 1u)) >> 16;   // RNE
  return (unsigned short)r;
}

__device__ __forceinline__ unsigned long long pack4bf(float4 v) {
  unsigned long long a = f2bf(v.x), b = f2bf(v.y), c = f2bf(v.z), d = f2bf(v.w);
  return a | (b << 16) | (c << 32) | (d << 48);
}

__device__ __forceinline__ void gll16(const void* gsrc, void* ldst) {
  __builtin_amdgcn_global_load_lds(
      (const __attribute__((address_space(1))) unsigned int*)gsrc,
      (__attribute__((address_space(3))) unsigned int*)ldst,
      16, 0, 0);
}

// ---- rmsnorm (tail rows only; row = by*1024 + rowBase + bx) ---------------

__global__ __launch_bounds__(256)
void rmsnorm_k(const float* __restrict__ X, const float* __restrict__ w,
               unsigned short* __restrict__ out, int rowBase) {
  const long row = (long)blockIdx.y * 1024 + rowBase + blockIdx.x;
  const float* x = X + row * Dsz;
  float4 v = ((const float4*)x)[threadIdx.x];
  float ss = v.x * v.x + v.y * v.y + v.z * v.z + v.w * v.w;
#pragma unroll
  for (int off = 32; off > 0; off >>= 1) ss += __shfl_down(ss, off);
  __shared__ float red[4];
  if ((threadIdx.x & 63) == 0) red[threadIdx.x >> 6] = ss;
  __syncthreads();
  float tot = red[0] + red[1] + red[2] + red[3];
  float scale = 1.0f / sqrtf(tot * (1.0f / Dsz) + 1e-6f);
  float4 wv = ((const float4*)w)[threadIdx.x];
  ushort4 o;
  o.x = f2bf(v.x * scale * wv.x); o.y = f2bf(v.y * scale * wv.y);
  o.z = f2bf(v.z * scale * wv.z); o.w = f2bf(v.w * scale * wv.w);
  ((ushort4*)out)[row * 256 + threadIdx.x] = o;
}

// ---- fused persistent kernel ----------------------------------------------
// 256 blocks x 320 threads.
// Blocks 0..127  : r3 scan (waves 0-3 matvec + LDS flags, wave 4 scalar
//                  combine/tanh/PLIF/publish). Additions: self-zero of its
//                  own Hex slots + SProg (before the init barrier, drained);
//                  Sout written as agent-scope u16 stores; per-step progress
//                  SProg[b][k]=t RELEASE (after Sout; after the critical
//                  relaxed Hex publish, so the scan path is unchanged).
// Blocks 128..255: (1) convert weff/gw to bf16 with agent u64 stores, tag
//                  ConvD[blk2]=MAGIC (release); (2) produce u (tagged Utag,
//                  as r7); (3) if j<JCUT: wait SProg >= 32j+32 (acquire,
//                  range-checked so poison/garbage can't pass), then a
//                  zero-LDS direct-fragment MFMA GEMM computes its 32 rows
//                  of x2 = x + syn*sigmoid(gate+gb), accumulates row ssq,
//                  rmsnorms -> y_bf; (4) convert wg/wu/wd (read only by
//                  later kernels -> plain stores fine).
// Replay/poison safety: all inter-block polls are tag-exact or
// range-checked; stale values from a prior replay are deterministic-
// identical, so early-pass reads return correct bytes.

__global__ __launch_bounds__(320)
void liquid_plif_k(const float* __restrict__ x,
                   const float* __restrict__ ln1_w,
                   const float* __restrict__ Wi,
                   const float* __restrict__ liq_b,
                   const float* __restrict__ Wr,
                   const float* __restrict__ liq_tau,
                   const float* __restrict__ plif_tau,
                   const float* __restrict__ gate_b,
                   const float* __restrict__ ln2_w,
                   unsigned long long* __restrict__ Hex,   // [2][B][D]
                   unsigned long long* __restrict__ Utag,  // [B][T][D]
                   unsigned short* __restrict__ Sout,      // (B,T,D) bf16
                   unsigned* __restrict__ SProg,           // [B][32]
                   unsigned* __restrict__ ConvD,           // [128]
                   float* __restrict__ x2_f,
                   unsigned short* __restrict__ y_bf,
                   const float* __restrict__ ffn_wg, unsigned short* wg_bf,
                   const float* __restrict__ ffn_wu, unsigned short* wu_bf,
                   const float* __restrict__ ffn_wd, unsigned short* wd_bf,
                   const float* __restrict__ gate_w, unsigned short* gw_bf,
                   const float* __restrict__ syn_w,  const void* mask,
                   unsigned short* weff_bf) {
  const int tid = threadIdx.x;

  __shared__ float h_lds[1024];
  __shared__ __align__(16) float red[2][4][8][4];
  __shared__ int flags[2][4];
  __shared__ float red4w[4];
  __shared__ float ssq_l[4][32];
  __shared__ int s_mode;

  if (tid < 8) ((int*)flags)[tid] = 0;

  if (blockIdx.x < 128) {
    // ===================== SCAN PATH ======================================
    const int blk = blockIdx.x;
    const int b = blk >> 5;
    const int base = (blk & 31) * 32;

    // self-zero own Hex slots (both parities) + own SProg entry
    if (tid < 64) {
      const long zp = (((long)(tid >> 5) * Bsz + b) << 10) + base + (tid & 31);
      __hip_atomic_store(&Hex[zp], 0ull, __ATOMIC_RELAXED, __HIP_MEMORY_SCOPE_AGENT);
    }
    if (tid == 64)
      __hip_atomic_store(&SProg[(b << 5) + (blk & 31)], 0u,
                         __ATOMIC_RELAXED, __HIP_MEMORY_SCOPE_AGENT);
    __syncthreads();   // drains the zero stores (vmcnt) before any publish

    if (tid < 256) {
      // ---- matvec waves ----
      const int l = tid & 63, w = tid >> 6;
      const int rg = tid & 7;
      const int ck = tid >> 3;
      const int win = 256 * w;

      float4 wr[4][8];
#pragma unroll
      for (int r = 0; r < 4; ++r) {
        const float* wrow = Wr + (long)(base + rg * 4 + r) * Dsz + ck * 32;
#pragma unroll
        for (int qq = 0; qq < 8; ++qq) {
          int q = (qq + ck) & 7;
          wr[r][qq] = *(const float4*)(wrow + q * 4);
        }
      }

      for (int t = 1; t <= Tsz; ++t) {
        const unsigned want = (unsigned)(t - 1);
        const unsigned long long* src =
            Hex + (((long)((t - 1) & 1) * Bsz + b) << 10) + win;
        unsigned long long a0, a1, a2, a3;
        for (;;) {
          a0 = __hip_atomic_load(src + l,       __ATOMIC_RELAXED, __HIP_MEMORY_SCOPE_AGENT);
          a1 = __hip_atomic_load(src + l + 64,  __ATOMIC_RELAXED, __HIP_MEMORY_SCOPE_AGENT);
          a2 = __hip_atomic_load(src + l + 128, __ATOMIC_RELAXED, __HIP_MEMORY_SCOPE_AGENT);
          a3 = __hip_atomic_load(src + l + 192, __ATOMIC_RELAXED, __HIP_MEMORY_SCOPE_AGENT);
          int ok = ((unsigned)(a0 >> 32) == want) & ((unsigned)(a1 >> 32) == want) &
                   ((unsigned)(a2 >> 32) == want) & ((unsigned)(a3 >> 32) == want);
          if (__all(ok)) break;
        }
        h_lds[win + l]       = __uint_as_float((unsigned)a0);
        h_lds[win + l + 64]  = __uint_as_float((unsigned)a1);
        h_lds[win + l + 128] = __uint_as_float((unsigned)a2);
        h_lds[win + l + 192] = __uint_as_float((unsigned)a3);

        float acc0 = 0.f, acc1 = 0.f, acc2 = 0.f, acc3 = 0.f;
        const float* hch = &h_lds[ck * 32];
#pragma unroll
        for (int qq = 0; qq < 8; ++qq) {
          const int q = (qq + ck) & 7;
          float4 hv = *(const float4*)(hch + q * 4);
          acc0 += wr[0][qq].x * hv.x + wr[0][qq].y * hv.y + wr[0][qq].z * hv.z + wr[0][qq].w * hv.w;
          acc1 += wr[1][qq].x * hv.x + wr[1][qq].y * hv.y + wr[1][qq].z * hv.z + wr[1][qq].w * hv.w;
          acc2 += wr[2][qq].x * hv.x + wr[2][qq].y * hv.y + wr[2][qq].z * hv.z + wr[2][qq].w * hv.w;
          acc3 += wr[3][qq].x * hv.x + wr[3][qq].y * hv.y + wr[3][qq].z * hv.z + wr[3][qq].w * hv.w;
        }
        acc0 += __shfl_xor(acc0, 8); acc0 += __shfl_xor(acc0, 16); acc0 += __shfl_xor(acc0, 32);
        acc1 += __shfl_xor(acc1, 8); acc1 += __shfl_xor(acc1, 16); acc1 += __shfl_xor(acc1, 32);
        acc2 += __shfl_xor(acc2, 8); acc2 += __shfl_xor(acc2, 16); acc2 += __shfl_xor(acc2, 32);
        acc3 += __shfl_xor(acc3, 8); acc3 += __shfl_xor(acc3, 16); acc3 += __shfl_xor(acc3, 32);
        if ((l & 56) == 0) {
          float4 rv; rv.x = acc0; rv.y = acc1; rv.z = acc2; rv.w = acc3;
          *(float4*)&red[t & 1][w][rg][0] = rv;
        }
        asm volatile("s_waitcnt lgkmcnt(0)" ::: "memory");
        if (l == 0)
          __hip_atomic_store(&flags[t & 1][w], t, __ATOMIC_RELEASE,
                             __HIP_MEMORY_SCOPE_WORKGROUP);
      }
    } else {
      // ---- scalar wave ----
      const int r = tid - 256;  // active lanes r<32
      float hstate = 0.f, vstate = 0.f, dec = 0.f, omdec = 0.f, itau = 0.f;
      if (r < 32) {
        float tau = liq_tau[base + r];
        dec = expf(-1.0f / tau);
        omdec = 1.0f - dec;
        itau = 1.0f / plif_tau[0];
      }
      for (int t = 1; t <= Tsz; ++t) {
        float uval = 0.f;
        if (r < 32) {   // tagged poll on producer output (usually ready)
          const unsigned long long* up =
              Utag + ((long)b * Tsz + (t - 1)) * Dsz + base + r;
          unsigned long long uv;
          do {
            uv = __hip_atomic_load(up, __ATOMIC_RELAXED, __HIP_MEMORY_SCOPE_AGENT);
          } while ((unsigned)(uv >> 32) != (unsigned)t);
          uval = __uint_as_float((unsigned)uv);
        }
        const int p = t & 1;
        for (;;) {
          int f0 = __hip_atomic_load(&flags[p][0], __ATOMIC_ACQUIRE, __HIP_MEMORY_SCOPE_WORKGROUP);
          int f1 = __hip_atomic_load(&flags[p][1], __ATOMIC_ACQUIRE, __HIP_MEMORY_SCOPE_WORKGROUP);
          int f2 = __hip_atomic_load(&flags[p][2], __ATOMIC_ACQUIRE, __HIP_MEMORY_SCOPE_WORKGROUP);
          int f3 = __hip_atomic_load(&flags[p][3], __ATOMIC_ACQUIRE, __HIP_MEMORY_SCOPE_WORKGROUP);
          if ((f0 == t) & (f1 == t) & (f2 == t) & (f3 == t)) break;
        }
        if (r < 32) {
          const int r2 = r >> 2, jj = r & 3;
          float sum = red[p][0][r2][jj] + red[p][1][r2][jj] +
                      red[p][2][r2][jj] + red[p][3][r2][jj];
          float z = sum + uval;
          float ex = __expf(2.0f * z);
          float f = 1.0f - 2.0f * __builtin_amdgcn_rcpf(ex + 1.0f);
          hstate = hstate * dec + omdec * f;
          vstate += (hstate - vstate) * itau;
          float sp = ((vstate - 0.05f) > 0.f) ? 1.f : 0.f;
          vstate -= sp * 0.05f;
          const long pidx = (((long)p * Bsz + b) << 10) + base + r;
          unsigned long long pv =
              (((unsigned long long)(unsigned)t) << 32) |
              (unsigned long long)__float_as_uint(hstate);
          // critical publish first (relaxed, fast)
          __hip_atomic_store(&Hex[pidx], pv, __ATOMIC_RELAXED,
                             __HIP_MEMORY_SCOPE_AGENT);
          // spike output: agent-scope u16 so same-kernel cross-XCD workers
          // can read it after the SProg release/acquire pair
          __hip_atomic_store(&Sout[((long)b * Tsz + (t - 1)) * Dsz + base + r],
                             (unsigned short)((sp > 0.f) ? 0x3F80 : 0),
                             __ATOMIC_RELAXED, __HIP_MEMORY_SCOPE_AGENT);
          if (r == 0)   // release: wave-level vmcnt drain orders all Sout
            __hip_atomic_store(&SProg[(b << 5) + (blk & 31)], (unsigned)t,
                               __ATOMIC_RELEASE, __HIP_MEMORY_SCOPE_AGENT);
        }
      }
    }
  } else {
    // ===================== PRODUCER / WORKER PATH =========================
    const int blk2 = blockIdx.x - 128;   // 0..127
    const int b = blk2 >> 5;
    const int base = (blk2 & 31) * 32;
    const int l = tid & 63, w = tid >> 6;

    // ---- (1) convert weff + gw early (agent u64 stores), tag ConvD -------
    if (tid == 0) {
      int md = 0;
      const unsigned* m = (const unsigned*)mask;
      for (int i = 0; i < 256; ++i) {
        unsigned wd = m[i];
        if (wd == 0x3F800000u) { md = 2; break; }
        if (wd > 1u) md = 1;
      }
      s_mode = md;
    }
    __syncthreads();
    {
      const int md = s_mode;
      const long gt = (long)blk2 * 320 + tid, gs = 128 * 320;
      const int n4 = Dsz * Dsz / 4;
      for (long i = gt; i < n4; i += gs) {
        float4 g = ((const float4*)gate_w)[i];
        __hip_atomic_store((unsigned long long*)gw_bf + i, pack4bf(g),
                           __ATOMIC_RELAXED, __HIP_MEMORY_SCOPE_AGENT);
        float4 s = ((const float4*)syn_w)[i];
        bool on0, on1, on2, on3;
        if (md == 1) {
          const unsigned char* mp = (const unsigned char*)mask + i * 4;
          on0 = mp[0]; on1 = mp[1]; on2 = mp[2]; on3 = mp[3];
        } else if (md == 2) {
          const float* mp = (const float*)mask + i * 4;
          on0 = mp[0] != 0.f; on1 = mp[1] != 0.f; on2 = mp[2] != 0.f; on3 = mp[3] != 0.f;
        } else {
          const int* mp = (const int*)mask + i * 4;
          on0 = mp[0]; on1 = mp[1]; on2 = mp[2]; on3 = mp[3];
        }
        float4 sv;
        sv.x = on0 ? s.x : 0.f; sv.y = on1 ? s.y : 0.f;
        sv.z = on2 ? s.z : 0.f; sv.w = on3 ? s.w : 0.f;
        __hip_atomic_store((unsigned long long*)weff_bf + i, pack4bf(sv),
                           __ATOMIC_RELAXED, __HIP_MEMORY_SCOPE_AGENT);
      }
    }
    __syncthreads();
    if (tid == 0)
      __hip_atomic_store(&ConvD[blk2], MAGICC, __ATOMIC_RELEASE,
                         __HIP_MEMORY_SCOPE_AGENT);

    // ---- (2) u-production (r7 verbatim) ----------------------------------
    const int rg = tid & 7;
    const int ck = tid >> 3;
    float4 wi[4][8];
    if (tid < 256) {
#pragma unroll
      for (int r = 0; r < 4; ++r) {
        const float* wrow = Wi + (long)(base + rg * 4 + r) * Dsz + ck * 32;
#pragma unroll
        for (int qq = 0; qq < 8; ++qq) {
          int q = (qq + ck) & 7;
          wi[r][qq] = *(const float4*)(wrow + q * 4);
        }
      }
    }
    float4 w4 = (tid < 256) ? ((const float4*)ln1_w)[tid] : float4{0, 0, 0, 0};
    float lb = 0.f;
    if (tid >= 256 && (tid - 256) < 32) lb = liq_b[base + (tid - 256)];

    for (int t = 1; t <= Tsz; ++t) {
      float4 xv = {0, 0, 0, 0};
      if (tid < 256) {
        xv = ((const float4*)(x + ((long)b * Tsz + (t - 1)) * Dsz))[tid];
        float ss = xv.x * xv.x + xv.y * xv.y + xv.z * xv.z + xv.w * xv.w;
#pragma unroll
        for (int off = 32; off > 0; off >>= 1) ss += __shfl_down(ss, off);
        if (l == 0) red4w[w] = ss;
      }
      __syncthreads();
      if (tid < 256) {
        float tot = red4w[0] + red4w[1] + red4w[2] + red4w[3];
        float scale = 1.0f / sqrtf(tot * (1.0f / Dsz) + 1e-6f);
        float4 av;
        av.x = xv.x * scale * w4.x; av.y = xv.y * scale * w4.y;
        av.z = xv.z * scale * w4.z; av.w = xv.w * scale * w4.w;
        ((float4*)h_lds)[tid] = av;
      }
      __syncthreads();
      if (tid < 256) {
        float acc0 = 0.f, acc1 = 0.f, acc2 = 0.f, acc3 = 0.f;
        const float* hch = &h_lds[ck * 32];
#pragma unroll
        for (int qq = 0; qq < 8; ++qq) {
          const int q = (qq + ck) & 7;
          float4 hv = *(const float4*)(hch + q * 4);
          acc0 += wi[0][qq].x * hv.x + wi[0][qq].y * hv.y + wi[0][qq].z * hv.z + wi[0][qq].w * hv.w;
          acc1 += wi[1][qq].x * hv.x + wi[1][qq].y * hv.y + wi[1][qq].z * hv.z + wi[1][qq].w * hv.w;
          acc2 += wi[2][qq].x * hv.x + wi[2][qq].y * hv.y + wi[2][qq].z * hv.z + wi[2][qq].w * hv.w;
          acc3 += wi[3][qq].x * hv.x + wi[3][qq].y * hv.y + wi[3][qq].z * hv.z + wi[3][qq].w * hv.w;
        }
        acc0 += __shfl_xor(acc0, 8); acc0 += __shfl_xor(acc0, 16); acc0 += __shfl_xor(acc0, 32);
        acc1 += __shfl_xor(acc1, 8); acc1 += __shfl_xor(acc1, 16); acc1 += __shfl_xor(acc1, 32);
        acc2 += __shfl_xor(acc2, 8); acc2 += __shfl_xor(acc2, 16); acc2 += __shfl_xor(acc2, 32);
        acc3 += __shfl_xor(acc3, 8); acc3 += __shfl_xor(acc3, 16); acc3 += __shfl_xor(acc3, 32);
        if ((l & 56) == 0) {
          float4 rv; rv.x = acc0; rv.y = acc1; rv.z = acc2; rv.w = acc3;
          *(float4*)&red[0][w][rg][0] = rv;
        }
      }
      __syncthreads();
      if (tid >= 256) {
        const int r = tid - 256;
        if (r < 32) {
          const int r2 = r >> 2, jj = r & 3;
          float sum = red[0][0][r2][jj] + red[0][1][r2][jj] +
                      red[0][2][r2][jj] + red[0][3][r2][jj] + lb;
          unsigned long long pv =
              (((unsigned long long)(unsigned)t) << 32) |
              (unsigned long long)__float_as_uint(sum);
          __hip_atomic_store(&Utag[((long)b * Tsz + (t - 1)) * Dsz + base + r],
                             pv, __ATOMIC_RELAXED, __HIP_MEMORY_SCOPE_AGENT);
        }
      }
      __syncthreads();
    }

    // ---- (3) syn/gate + rmsnorm for own 32 rows (j < JCUT) ---------------
    const int j = blk2 & 31;
    if (j < JCUT) {
      const unsigned t_hi = (unsigned)(j * 32 + 32);
      const long r0g = (long)b * 1024 + j * 32;   // first M-row

      // converts done? (tagged; stale==MAGIC is deterministic-safe)
      for (;;) {
        unsigned c0 = __hip_atomic_load(&ConvD[l], __ATOMIC_ACQUIRE, __HIP_MEMORY_SCOPE_AGENT);
        unsigned c1 = __hip_atomic_load(&ConvD[l + 64], __ATOMIC_ACQUIRE, __HIP_MEMORY_SCOPE_AGENT);
        if (__all((c0 == MAGICC) & (c1 == MAGICC))) break;
      }
      // scan progress (range check rejects poison/garbage)
      for (;;) {
        unsigned pk = __hip_atomic_load(&SProg[(b << 5) + (l & 31)],
                                        __ATOMIC_ACQUIRE, __HIP_MEMORY_SCOPE_AGENT);
        if (__all((pk >= t_hi) & (pk <= (unsigned)Tsz))) break;
      }

      float ssq8[8] = {0.f, 0.f, 0.f, 0.f, 0.f, 0.f, 0.f, 0.f};
      if (tid < 256) {
        // direct-fragment GEMM: out 32 x 1024, K=1024, B-mats {weff, gw}
        const int cw = w * 64;                   // wave col offset in 256-tile
#pragma unroll 1
        for (int bn = 0; bn < 4; ++bn) {
          const int cbase = bn * 256 + cw;
          floatx4_t acc[2][2][4];
#pragma unroll
          for (int mt = 0; mt < 2; ++mt)
#pragma unroll
            for (int m = 0; m < 2; ++m)
#pragma unroll
              for (int n = 0; n < 4; ++n) acc[mt][m][n] = (floatx4_t)(0.f);
          const int fr = (l & 15), fk = (l >> 4) * 8;
#pragma unroll 2
          for (int kc = 0; kc < 32; ++kc) {
            const int ko = kc * 32 + fk;
            short8 af0 = *(const short8*)&Sout[(r0g + fr) * Dsz + ko];
            short8 af1 = *(const short8*)&Sout[(r0g + 16 + fr) * Dsz + ko];
#pragma unroll
            for (int n = 0; n < 4; ++n) {
              const long brow = (long)(cbase + n * 16 + fr) * Dsz + ko;
              short8 bf0 = *(const short8*)&weff_bf[brow];
              short8 bf1 = *(const short8*)&gw_bf[brow];
              acc[0][0][n] = __builtin_amdgcn_mfma_f32_16x16x32_bf16(af0, bf0, acc[0][0][n], 0, 0, 0);
              acc[0][1][n] = __builtin_amdgcn_mfma_f32_16x16x32_bf16(af1, bf0, acc[0][1][n], 0, 0, 0);
              acc[1][0][n] = __builtin_amdgcn_mfma_f32_16x16x32_bf16(af0, bf1, acc[1][0][n], 0, 0, 0);
              acc[1][1][n] = __builtin_amdgcn_mfma_f32_16x16x32_bf16(af1, bf1, acc[1][1][n], 0, 0, 0);
            }
          }
          // epilogue for this bn
#pragma unroll
          for (int m = 0; m < 2; ++m)
#pragma unroll
            for (int n = 0; n < 4; ++n) {
              const int c = cbase + n * 16 + fr;
#pragma unroll
              for (int q = 0; q < 4; ++q) {
                const int r = m * 16 + (l >> 4) * 4 + q;
                const long idx = (r0g + r) * Dsz + c;
                float gsum = acc[1][m][n][q] + gate_b[c];
                float sg = 1.f / (1.f + __expf(-gsum));
                float x2v = x[idx] + acc[0][m][n][q] * sg;
                x2_f[idx] = x2v;
                ssq8[m * 4 + q] += x2v * x2v;
              }
            }
        }
        // reduce ssq over the 16 lanes sharing (l>>4)
#pragma unroll
        for (int i = 0; i < 8; ++i) {
          float v = ssq8[i];
          v += __shfl_xor(v, 1); v += __shfl_xor(v, 2);
          v += __shfl_xor(v, 4); v += __shfl_xor(v, 8);
          ssq8[i] = v;
        }
        if ((l & 15) == 0) {
#pragma unroll
          for (int m = 0; m < 2; ++m)
#pragma unroll
            for (int q = 0; q < 4; ++q)
              ssq_l[w][m * 16 + (l >> 4) * 4 + q] = ssq8[m * 4 + q];
        }
      }
      __syncthreads();   // x2 stores drained; ssq_l visible
      if (tid < 256) {
        const int row = tid >> 3, cg = tid & 7;
        float tot = ssq_l[0][row] + ssq_l[1][row] + ssq_l[2][row] + ssq_l[3][row];
        float scale = 1.0f / sqrtf(tot * (1.0f / Dsz) + 1e-6f);
        const long gr = r0g + row;
#pragma unroll 4
        for (int i = 0; i < 32; ++i) {
          const int c = cg * 128 + i * 4;
          float4 xv = *(const float4*)&x2_f[gr * Dsz + c];
          float4 wv = *(const float4*)&ln2_w[c];
          ushort4 o;
          o.x = f2bf(xv.x * scale * wv.x); o.y = f2bf(xv.y * scale * wv.y);
          o.z = f2bf(xv.z * scale * wv.z); o.w = f2bf(xv.w * scale * wv.w);
          *(ushort4*)&y_bf[gr * Dsz + c] = o;
        }
      }
    }

    // ---- (4) big weight converts (read only by later kernels) ------------
    {
      const long gt = (long)blk2 * 320 + tid, gs = 128 * 320;
      const int n4big = Hsz * Dsz / 4;
      for (long i = gt; i < n4big; i += gs) {
        float4 v = ((const float4*)ffn_wg)[i];
        ushort4 o; o.x = f2bf(v.x); o.y = f2bf(v.y); o.z = f2bf(v.z); o.w = f2bf(v.w);
        ((ushort4*)wg_bf)[i] = o;
        v = ((const float4*)ffn_wu)[i];
        o.x = f2bf(v.x); o.y = f2bf(v.y); o.z = f2bf(v.z); o.w = f2bf(v.w);
        ((ushort4*)wu_bf)[i] = o;
        v = ((const float4*)ffn_wd)[i];
        o.x = f2bf(v.x); o.y = f2bf(v.y); o.z = f2bf(v.z); o.w = f2bf(v.w);
        ((ushort4*)wd_bf)[i] = o;
      }
    }
  }
}

// ---- bf16 MFMA GEMM, C = A @ B^T, m97-style 128x128x32 tile ---------------
// rowStart = (bm/R)*1024 + rowBase + (bm%R)*128  (R=8,rowBase=0 -> bm*128)
// EPI 1: out f32 = aux0 + acc0 * sigmoid(acc1 + aux1[col])
// EPI 2: out bf16 = silu(acc0) * acc1
// EPI 3: out f32 = aux0 + acc0

template<int NB, int EPI>
__global__ __launch_bounds__(256)
void gemm_bt(const unsigned short* __restrict__ A,
             const unsigned short* __restrict__ B0,
             const unsigned short* __restrict__ B1,
             const float* __restrict__ aux0, const float* __restrict__ aux1,
             void* __restrict__ outp, int M, int N, int K,
             int R, int rowBase) {
  __shared__ unsigned short sA[128 * 32];
  __shared__ unsigned short sB[2 * 128 * 32];
  const int tid = threadIdx.x;
  const int w = tid >> 6, l = tid & 63;
  const int wm = w & 1, wn = w >> 1;
  const int bm = blockIdx.x, bn = blockIdx.y;
  const int rowStart = (bm / R) * 1024 + rowBase + (bm % R) * 128;

  floatx4_t acc[NB][4][4];
#pragma unroll
  for (int j = 0; j < NB; ++j)
#pragma unroll
    for (int m = 0; m < 4; ++m)
#pragma unroll
      for (int n = 0; n < 4; ++n) acc[j][m][n] = (floatx4_t)(0.f);

  const int rA = rowStart + 16 * w + (l >> 2);
  const int rB = bn * 128 + 16 * w + (l >> 2);
  const int kl = (l & 3) * 8;
  const unsigned short* gA = A + (long)rA * K + kl;
  const unsigned short* gB0 = B0 + (long)rB * K + kl;
  const unsigned short* gB1 = nullptr;
  if constexpr (NB > 1) gB1 = B1 + (long)rB * K + kl;
  unsigned short* lA = &sA[(16 * w) * 32];
  unsigned short* lB = &sB[(16 * w) * 32];

  for (int k0 = 0; k0 < K; k0 += 32) {
    gll16(gA + k0,              lA);
    gll16(gA + k0 + 64 * K,     lA + 64 * 32);
    gll16(gB0 + k0,             lB);
    gll16(gB0 + k0 + 64 * K,    lB + 64 * 32);
    if constexpr (NB > 1) {
      gll16(gB1 + k0,           lB + 128 * 32);
      gll16(gB1 + k0 + 64 * K,  lB + 192 * 32);
    }
    __syncthreads();
    short8 af[4];
#pragma unroll
    for (int m = 0; m < 4; ++m)
      af[m] = *(const short8*)&sA[(wm * 64 + m * 16 + (l & 15)) * 32 + (l >> 4) * 8];
#pragma unroll
    for (int j = 0; j < NB; ++j) {
#pragma unroll
      for (int n = 0; n < 4; ++n) {
        short8 bf = *(const short8*)&sB[j * 128 * 32 +
                        (wn * 64 + n * 16 + (l & 15)) * 32 + (l >> 4) * 8];
#pragma unroll
        for (int m = 0; m < 4; ++m)
          acc[j][m][n] = __builtin_amdgcn_mfma_f32_16x16x32_bf16(
              af[m], bf, acc[j][m][n], 0, 0, 0);
      }
    }
    __syncthreads();
  }

  const int colBase = bn * 128 + wn * 64;
  const int rowBase2 = rowStart + wm * 64;
#pragma unroll
  for (int m = 0; m < 4; ++m) {
#pragma unroll
    for (int n = 0; n < 4; ++n) {
      const int col = colBase + n * 16 + (l & 15);
#pragma unroll
      for (int j = 0; j < 4; ++j) {
        const int row = rowBase2 + m * 16 + (l >> 4) * 4 + j;
        const long idx = (long)row * N + col;
        float v0 = acc[0][m][n][j];
        if constexpr (EPI == 1) {
          float gsum = acc[NB - 1][m][n][j] + aux1[col];
          float sg = 1.f / (1.f + __expf(-gsum));
          ((float*)outp)[idx] = aux0[idx] + v0 * sg;
        } else if constexpr (EPI == 2) {
          float sil = v0 / (1.f + __expf(-v0));
          ((unsigned short*)outp)[idx] = f2bf(sil * acc[NB - 1][m][n][j]);
        } else {  // EPI == 3
          ((float*)outp)[idx] = aux0[idx] + v0;
        }
      }
    }
  }
}

// ---------------------------------------------------------------------------

extern "C" void kernel_launch(void* const* d_in, const int* in_sizes, int n_in,
                              void* d_out, int out_size, void* d_ws, size_t ws_size,
                              hipStream_t stream) {
  (void)in_sizes; (void)n_in; (void)out_size; (void)ws_size;

  const float* x        = (const float*)d_in[0];
  const float* ln1_w    = (const float*)d_in[1];
  const float* liq_Wi   = (const float*)d_in[2];
  const float* liq_Wr   = (const float*)d_in[3];
  const float* liq_b    = (const float*)d_in[4];
  const float* liq_tau  = (const float*)d_in[5];
  const float* plif_tau = (const float*)d_in[6];
  const float* syn_w    = (const float*)d_in[7];
  const float* gate_w   = (const float*)d_in[8];
  const float* gate_b   = (const float*)d_in[9];
  const float* ln2_w    = (const float*)d_in[10];
  const float* ffn_wg   = (const float*)d_in[11];
  const float* ffn_wu   = (const float*)d_in[12];
  const float* ffn_wd   = (const float*)d_in[13];
  const void*  mask     = d_in[14];

  char* ws = (char*)d_ws;
  const size_t MB = 1024ull * 1024ull;
  unsigned short* wg_bf   = (unsigned short*)(ws + 0 * MB);    // 16 MB
  unsigned short* wu_bf   = (unsigned short*)(ws + 16 * MB);   // 16 MB
  unsigned short* wd_bf   = (unsigned short*)(ws + 32 * MB);   // 16 MB
  unsigned short* weff_bf = (unsigned short*)(ws + 48 * MB);   // 2 MB
  unsigned short* gw_bf   = (unsigned short*)(ws + 50 * MB);   // 2 MB
  float*          x2_f    = (float*)         (ws + 52 * MB);   // 16 MB
  unsigned short* s_bf    = (unsigned short*)(ws + 68 * MB);   // 8 MB
  unsigned short* y_bf    = (unsigned short*)(ws + 76 * MB);   // 8 MB
  unsigned short* ff_bf   = (unsigned short*)(ws + 84 * MB);   // 64 MB (84-148)
  unsigned long long* Utag= (unsigned long long*)(ws + 84 * MB); // 32 MB,
                                    // overlaps ff_bf: Utag dead before FFN
  unsigned long long* hex = (unsigned long long*)(ws + 148 * MB); // 64 KB
  unsigned*       SProg   = (unsigned*)(ws + 148 * MB + 65536);   // 512 B
  unsigned*       ConvD   = (unsigned*)(ws + 148 * MB + 66048);   // 512 B
  float*          out_f   = (float*)d_out;

  const int M = Bsz * Tsz;  // 4096

  // fused: scan (blocks 0-127; self-zeroes Hex/SProg) + producers/workers
  liquid_plif_k<<<256, 320, 0, stream>>>(
      x, ln1_w, liq_Wi, liq_b, liq_Wr, liq_tau, plif_tau, gate_b, ln2_w,
      hex, Utag, s_bf, SProg, ConvD, x2_f, y_bf,
      ffn_wg, wg_bf, ffn_wu, wu_bf, ffn_wd, wd_bf, gate_w, gw_bf,
      syn_w, mask, weff_bf);

  // tail rows [768,1024) per batch: syn/gate + rmsnorm
  gemm_bt<2, 1><<<dim3(8, Dsz / 128), 256, 0, stream>>>(
      s_bf, weff_bf, gw_bf, x, gate_b, x2_f, M, Dsz, Dsz, 2, JCUT * 32);
  rmsnorm_k<<<dim3(256, 4), 256, 0, stream>>>(x2_f, ln2_w, y_bf, JCUT * 32);

  // ff = silu(y@wg^T) * (y@wu^T)  (bf16, full M)
  gemm_bt<2, 2><<<dim3(M / 128, Hsz / 128), 256, 0, stream>>>(
      y_bf, wg_bf, wu_bf, nullptr, nullptr, ff_bf, M, Hsz, Dsz, 8, 0);

  // out = x2 + ff @ wd^T  (f32, full M)
  gemm_bt<1, 3><<<dim3(M / 128, Dsz / 128), 256, 0, stream>>>(
      ff_bf, wd_bf, nullptr, x2_f, nullptr, out_f, M, Dsz, Hsz, 8, 0);
}

// Round 9
// 2286.657 us; speedup vs baseline: 1.8333x; 1.8333x over previous
//
#include <hip/hip_runtime.h>
#include <math.h>

// ---------------------------------------------------------------------------
// HybridBlock: rmsnorm -> LiquidCell scan -> PLIF scan -> sparse synapse +
// sigmoid gate (residual) -> rmsnorm -> SwiGLU-style FFN (residual).
// B=4, T=1024, D=1024, H=8192.
// ---------------------------------------------------------------------------

#define Bsz 4
#define Tsz 1024
#define Dsz 1024
#define Hsz 8192
#define JCUT 24                 // workers handle t-chunks j<24; post-kernels the rest
#define MAGICC 0x5EEDC0DEu
#define PTAG   0xA5E00000u      // SProg tag (high 20 bits), t in low 12

typedef __attribute__((ext_vector_type(8))) short short8;
typedef __attribute__((ext_vector_type(4))) float floatx4_t;

// ---- helpers --------------------------------------------------------------

__device__ __forceinline__ unsigned short f2bf(float f) {
  union { float f; unsigned u; } c; c.f = f;
  unsigned x = c.u;
  unsigned r = (x + 0x7FFFu + ((x >> 16) & 1u)) >> 16;   // RNE
  return (unsigned short)r;
}

__device__ __forceinline__ unsigned long long pack4bf(float4 v) {
  unsigned long long a = f2bf(v.x), b = f2bf(v.y), c = f2bf(v.z), d = f2bf(v.w);
  return a | (b << 16) | (c << 32) | (d << 48);
}

__device__ __forceinline__ void gll16(const void* gsrc, void* ldst) {
  __builtin_amdgcn_global_load_lds(
      (const __attribute__((address_space(1))) unsigned int*)gsrc,
      (__attribute__((address_space(3))) unsigned int*)ldst,
      16, 0, 0);
}

// ---- rmsnorm (tail rows only; row = by*1024 + rowBase + bx) ---------------

__global__ __launch_bounds__(256)
void rmsnorm_k(const float* __restrict__ X, const float* __restrict__ w,
               unsigned short* __restrict__ out, int rowBase) {
  const long row = (long)blockIdx.y * 1024 + rowBase + blockIdx.x;
  const float* x = X + row * Dsz;
  float4 v = ((const float4*)x)[threadIdx.x];
  float ss = v.x * v.x + v.y * v.y + v.z * v.z + v.w * v.w;
#pragma unroll
  for (int off = 32; off > 0; off >>= 1) ss += __shfl_down(ss, off);
  __shared__ float red[4];
  if ((threadIdx.x & 63) == 0) red[threadIdx.x >> 6] = ss;
  __syncthreads();
  float tot = red[0] + red[1] + red[2] + red[3];
  float scale = 1.0f / sqrtf(tot * (1.0f / Dsz) + 1e-6f);
  float4 wv = ((const float4*)w)[threadIdx.x];
  ushort4 o;
  o.x = f2bf(v.x * scale * wv.x); o.y = f2bf(v.y * scale * wv.y);
  o.z = f2bf(v.z * scale * wv.z); o.w = f2bf(v.w * scale * wv.w);
  ((ushort4*)out)[row * 256 + threadIdx.x] = o;
}

// ---- fused persistent kernel ----------------------------------------------
// 256 blocks x 320 threads. Structure as r8 but with NO agent acquire/release
// in loops (on gfx950 those emit buffer_inv / buffer_wbl2 = full-L2
// cache-maintenance -> r8's 2x regression). All cross-block sync is relaxed
// LLC (sc1) ops with tag/retirement ordering:
//  - SProg[b][k] = PTAG|(t-32), relaxed. The 32-step lag IS the ordering:
//    vmcnt retires FIFO (<=63 outstanding) and the scalar wave issues >=4
//    VMEM ops/step, so when PTAG|(t-32) is issued (>=128 ops later), step
//    t-32's Sout sc1 stores are already ack'd at the LLC.
//  - Worker polls: relaxed loads + s_sleep; pattern+range check rejects
//    garbage/poison; stale cross-replay values are deterministic-identical.
//  - ConvD: relaxed store AFTER __syncthreads (barrier already drained the
//    convert stores -> ordering is by program structure, not a fence).

__global__ __launch_bounds__(320)
void liquid_plif_k(const float* __restrict__ x,
                   const float* __restrict__ ln1_w,
                   const float* __restrict__ Wi,
                   const float* __restrict__ liq_b,
                   const float* __restrict__ Wr,
                   const float* __restrict__ liq_tau,
                   const float* __restrict__ plif_tau,
                   const float* __restrict__ gate_b,
                   const float* __restrict__ ln2_w,
                   unsigned long long* __restrict__ Hex,   // [2][B][D]
                   unsigned long long* __restrict__ Utag,  // [B][T][D]
                   unsigned short* __restrict__ Sout,      // (B,T,D) bf16
                   unsigned* __restrict__ SProg,           // [B][32]
                   unsigned* __restrict__ ConvD,           // [128]
                   float* __restrict__ x2_f,
                   unsigned short* __restrict__ y_bf,
                   const float* __restrict__ ffn_wg, unsigned short* wg_bf,
                   const float* __restrict__ ffn_wu, unsigned short* wu_bf,
                   const float* __restrict__ ffn_wd, unsigned short* wd_bf,
                   const float* __restrict__ gate_w, unsigned short* gw_bf,
                   const float* __restrict__ syn_w,  const void* mask,
                   unsigned short* weff_bf) {
  const int tid = threadIdx.x;

  __shared__ float h_lds[1024];
  __shared__ __align__(16) float red[2][4][8][4];
  __shared__ int flags[2][4];
  __shared__ float red4w[4];
  __shared__ float ssq_l[4][32];
  __shared__ int s_mode;

  if (tid < 8) ((int*)flags)[tid] = 0;

  if (blockIdx.x < 128) {
    // ===================== SCAN PATH ======================================
    const int blk = blockIdx.x;
    const int b = blk >> 5;
    const int base = (blk & 31) * 32;

    // self-zero own Hex slots (both parities) + own SProg entry (tagged 0)
    if (tid < 64) {
      const long zp = (((long)(tid >> 5) * Bsz + b) << 10) + base + (tid & 31);
      __hip_atomic_store(&Hex[zp], 0ull, __ATOMIC_RELAXED, __HIP_MEMORY_SCOPE_AGENT);
    }
    if (tid == 64)
      __hip_atomic_store(&SProg[(b << 5) + (blk & 31)], PTAG,
                         __ATOMIC_RELAXED, __HIP_MEMORY_SCOPE_AGENT);
    __syncthreads();   // drains the zero stores (vmcnt) before any publish

    if (tid < 256) {
      // ---- matvec waves ----
      const int l = tid & 63, w = tid >> 6;
      const int rg = tid & 7;
      const int ck = tid >> 3;
      const int win = 256 * w;

      float4 wr[4][8];
#pragma unroll
      for (int r = 0; r < 4; ++r) {
        const float* wrow = Wr + (long)(base + rg * 4 + r) * Dsz + ck * 32;
#pragma unroll
        for (int qq = 0; qq < 8; ++qq) {
          int q = (qq + ck) & 7;
          wr[r][qq] = *(const float4*)(wrow + q * 4);
        }
      }

      for (int t = 1; t <= Tsz; ++t) {
        const unsigned want = (unsigned)(t - 1);
        const unsigned long long* src =
            Hex + (((long)((t - 1) & 1) * Bsz + b) << 10) + win;
        unsigned long long a0, a1, a2, a3;
        for (;;) {
          a0 = __hip_atomic_load(src + l,       __ATOMIC_RELAXED, __HIP_MEMORY_SCOPE_AGENT);
          a1 = __hip_atomic_load(src + l + 64,  __ATOMIC_RELAXED, __HIP_MEMORY_SCOPE_AGENT);
          a2 = __hip_atomic_load(src + l + 128, __ATOMIC_RELAXED, __HIP_MEMORY_SCOPE_AGENT);
          a3 = __hip_atomic_load(src + l + 192, __ATOMIC_RELAXED, __HIP_MEMORY_SCOPE_AGENT);
          int ok = ((unsigned)(a0 >> 32) == want) & ((unsigned)(a1 >> 32) == want) &
                   ((unsigned)(a2 >> 32) == want) & ((unsigned)(a3 >> 32) == want);
          if (__all(ok)) break;
        }
        h_lds[win + l]       = __uint_as_float((unsigned)a0);
        h_lds[win + l + 64]  = __uint_as_float((unsigned)a1);
        h_lds[win + l + 128] = __uint_as_float((unsigned)a2);
        h_lds[win + l + 192] = __uint_as_float((unsigned)a3);

        float acc0 = 0.f, acc1 = 0.f, acc2 = 0.f, acc3 = 0.f;
        const float* hch = &h_lds[ck * 32];
#pragma unroll
        for (int qq = 0; qq < 8; ++qq) {
          const int q = (qq + ck) & 7;
          float4 hv = *(const float4*)(hch + q * 4);
          acc0 += wr[0][qq].x * hv.x + wr[0][qq].y * hv.y + wr[0][qq].z * hv.z + wr[0][qq].w * hv.w;
          acc1 += wr[1][qq].x * hv.x + wr[1][qq].y * hv.y + wr[1][qq].z * hv.z + wr[1][qq].w * hv.w;
          acc2 += wr[2][qq].x * hv.x + wr[2][qq].y * hv.y + wr[2][qq].z * hv.z + wr[2][qq].w * hv.w;
          acc3 += wr[3][qq].x * hv.x + wr[3][qq].y * hv.y + wr[3][qq].z * hv.z + wr[3][qq].w * hv.w;
        }
        acc0 += __shfl_xor(acc0, 8); acc0 += __shfl_xor(acc0, 16); acc0 += __shfl_xor(acc0, 32);
        acc1 += __shfl_xor(acc1, 8); acc1 += __shfl_xor(acc1, 16); acc1 += __shfl_xor(acc1, 32);
        acc2 += __shfl_xor(acc2, 8); acc2 += __shfl_xor(acc2, 16); acc2 += __shfl_xor(acc2, 32);
        acc3 += __shfl_xor(acc3, 8); acc3 += __shfl_xor(acc3, 16); acc3 += __shfl_xor(acc3, 32);
        if ((l & 56) == 0) {
          float4 rv; rv.x = acc0; rv.y = acc1; rv.z = acc2; rv.w = acc3;
          *(float4*)&red[t & 1][w][rg][0] = rv;
        }
        asm volatile("s_waitcnt lgkmcnt(0)" ::: "memory");
        if (l == 0)
          __hip_atomic_store(&flags[t & 1][w], t, __ATOMIC_RELEASE,
                             __HIP_MEMORY_SCOPE_WORKGROUP);
      }
    } else {
      // ---- scalar wave ----
      const int r = tid - 256;  // active lanes r<32
      float hstate = 0.f, vstate = 0.f, dec = 0.f, omdec = 0.f, itau = 0.f;
      if (r < 32) {
        float tau = liq_tau[base + r];
        dec = expf(-1.0f / tau);
        omdec = 1.0f - dec;
        itau = 1.0f / plif_tau[0];
      }
      for (int t = 1; t <= Tsz; ++t) {
        float uval = 0.f;
        if (r < 32) {   // tagged poll on producer output (usually ready)
          const unsigned long long* up =
              Utag + ((long)b * Tsz + (t - 1)) * Dsz + base + r;
          unsigned long long uv;
          do {
            uv = __hip_atomic_load(up, __ATOMIC_RELAXED, __HIP_MEMORY_SCOPE_AGENT);
          } while ((unsigned)(uv >> 32) != (unsigned)t);
          uval = __uint_as_float((unsigned)uv);
        }
        const int p = t & 1;
        for (;;) {
          int f0 = __hip_atomic_load(&flags[p][0], __ATOMIC_ACQUIRE, __HIP_MEMORY_SCOPE_WORKGROUP);
          int f1 = __hip_atomic_load(&flags[p][1], __ATOMIC_ACQUIRE, __HIP_MEMORY_SCOPE_WORKGROUP);
          int f2 = __hip_atomic_load(&flags[p][2], __ATOMIC_ACQUIRE, __HIP_MEMORY_SCOPE_WORKGROUP);
          int f3 = __hip_atomic_load(&flags[p][3], __ATOMIC_ACQUIRE, __HIP_MEMORY_SCOPE_WORKGROUP);
          if ((f0 == t) & (f1 == t) & (f2 == t) & (f3 == t)) break;
        }
        if (r < 32) {
          const int r2 = r >> 2, jj = r & 3;
          float sum = red[p][0][r2][jj] + red[p][1][r2][jj] +
                      red[p][2][r2][jj] + red[p][3][r2][jj];
          float z = sum + uval;
          float ex = __expf(2.0f * z);
          float f = 1.0f - 2.0f * __builtin_amdgcn_rcpf(ex + 1.0f);
          hstate = hstate * dec + omdec * f;
          vstate += (hstate - vstate) * itau;
          float sp = ((vstate - 0.05f) > 0.f) ? 1.f : 0.f;
          vstate -= sp * 0.05f;
          const long pidx = (((long)p * Bsz + b) << 10) + base + r;
          unsigned long long pv =
              (((unsigned long long)(unsigned)t) << 32) |
              (unsigned long long)__float_as_uint(hstate);
          // critical publish first (relaxed, fast)
          __hip_atomic_store(&Hex[pidx], pv, __ATOMIC_RELAXED,
                             __HIP_MEMORY_SCOPE_AGENT);
          // spike output: sc1 (LLC) so cross-XCD workers read fresh bytes
          __hip_atomic_store(&Sout[((long)b * Tsz + (t - 1)) * Dsz + base + r],
                             (unsigned short)((sp > 0.f) ? 0x3F80 : 0),
                             __ATOMIC_RELAXED, __HIP_MEMORY_SCOPE_AGENT);
          // lagged progress: relaxed, NO fence (see header comment)
          if (r == 0 && t > 32)
            __hip_atomic_store(&SProg[(b << 5) + (blk & 31)],
                               PTAG | (unsigned)(t - 32),
                               __ATOMIC_RELAXED, __HIP_MEMORY_SCOPE_AGENT);
        }
      }
    }
  } else {
    // ===================== PRODUCER / WORKER PATH =========================
    const int blk2 = blockIdx.x - 128;   // 0..127
    const int b = blk2 >> 5;
    const int base = (blk2 & 31) * 32;
    const int l = tid & 63, w = tid >> 6;

    // ---- (1) convert weff + gw early (agent u64 stores), tag ConvD -------
    if (tid == 0) {
      int md = 0;
      const unsigned* m = (const unsigned*)mask;
      for (int i = 0; i < 256; ++i) {
        unsigned wd = m[i];
        if (wd == 0x3F800000u) { md = 2; break; }
        if (wd > 1u) md = 1;
      }
      s_mode = md;
    }
    __syncthreads();
    {
      const int md = s_mode;
      const long gt = (long)blk2 * 320 + tid, gs = 128 * 320;
      const int n4 = Dsz * Dsz / 4;
      for (long i = gt; i < n4; i += gs) {
        float4 g = ((const float4*)gate_w)[i];
        __hip_atomic_store((unsigned long long*)gw_bf + i, pack4bf(g),
                           __ATOMIC_RELAXED, __HIP_MEMORY_SCOPE_AGENT);
        float4 s = ((const float4*)syn_w)[i];
        bool on0, on1, on2, on3;
        if (md == 1) {
          const unsigned char* mp = (const unsigned char*)mask + i * 4;
          on0 = mp[0]; on1 = mp[1]; on2 = mp[2]; on3 = mp[3];
        } else if (md == 2) {
          const float* mp = (const float*)mask + i * 4;
          on0 = mp[0] != 0.f; on1 = mp[1] != 0.f; on2 = mp[2] != 0.f; on3 = mp[3] != 0.f;
        } else {
          const int* mp = (const int*)mask + i * 4;
          on0 = mp[0]; on1 = mp[1]; on2 = mp[2]; on3 = mp[3];
        }
        float4 sv;
        sv.x = on0 ? s.x : 0.f; sv.y = on1 ? s.y : 0.f;
        sv.z = on2 ? s.z : 0.f; sv.w = on3 ? s.w : 0.f;
        __hip_atomic_store((unsigned long long*)weff_bf + i, pack4bf(sv),
                           __ATOMIC_RELAXED, __HIP_MEMORY_SCOPE_AGENT);
      }
    }
    __syncthreads();   // drains convert stores -> ConvD store is ordered
    if (tid == 0)
      __hip_atomic_store(&ConvD[blk2], MAGICC, __ATOMIC_RELAXED,
                         __HIP_MEMORY_SCOPE_AGENT);

    // ---- (2) u-production (r7 verbatim) ----------------------------------
    const int rg = tid & 7;
    const int ck = tid >> 3;
    float4 wi[4][8];
    if (tid < 256) {
#pragma unroll
      for (int r = 0; r < 4; ++r) {
        const float* wrow = Wi + (long)(base + rg * 4 + r) * Dsz + ck * 32;
#pragma unroll
        for (int qq = 0; qq < 8; ++qq) {
          int q = (qq + ck) & 7;
          wi[r][qq] = *(const float4*)(wrow + q * 4);
        }
      }
    }
    float4 w4 = (tid < 256) ? ((const float4*)ln1_w)[tid] : float4{0, 0, 0, 0};
    float lb = 0.f;
    if (tid >= 256 && (tid - 256) < 32) lb = liq_b[base + (tid - 256)];

    for (int t = 1; t <= Tsz; ++t) {
      float4 xv = {0, 0, 0, 0};
      if (tid < 256) {
        xv = ((const float4*)(x + ((long)b * Tsz + (t - 1)) * Dsz))[tid];
        float ss = xv.x * xv.x + xv.y * xv.y + xv.z * xv.z + xv.w * xv.w;
#pragma unroll
        for (int off = 32; off > 0; off >>= 1) ss += __shfl_down(ss, off);
        if (l == 0) red4w[w] = ss;
      }
      __syncthreads();
      if (tid < 256) {
        float tot = red4w[0] + red4w[1] + red4w[2] + red4w[3];
        float scale = 1.0f / sqrtf(tot * (1.0f / Dsz) + 1e-6f);
        float4 av;
        av.x = xv.x * scale * w4.x; av.y = xv.y * scale * w4.y;
        av.z = xv.z * scale * w4.z; av.w = xv.w * scale * w4.w;
        ((float4*)h_lds)[tid] = av;
      }
      __syncthreads();
      if (tid < 256) {
        float acc0 = 0.f, acc1 = 0.f, acc2 = 0.f, acc3 = 0.f;
        const float* hch = &h_lds[ck * 32];
#pragma unroll
        for (int qq = 0; qq < 8; ++qq) {
          const int q = (qq + ck) & 7;
          float4 hv = *(const float4*)(hch + q * 4);
          acc0 += wi[0][qq].x * hv.x + wi[0][qq].y * hv.y + wi[0][qq].z * hv.z + wi[0][qq].w * hv.w;
          acc1 += wi[1][qq].x * hv.x + wi[1][qq].y * hv.y + wi[1][qq].z * hv.z + wi[1][qq].w * hv.w;
          acc2 += wi[2][qq].x * hv.x + wi[2][qq].y * hv.y + wi[2][qq].z * hv.z + wi[2][qq].w * hv.w;
          acc3 += wi[3][qq].x * hv.x + wi[3][qq].y * hv.y + wi[3][qq].z * hv.z + wi[3][qq].w * hv.w;
        }
        acc0 += __shfl_xor(acc0, 8); acc0 += __shfl_xor(acc0, 16); acc0 += __shfl_xor(acc0, 32);
        acc1 += __shfl_xor(acc1, 8); acc1 += __shfl_xor(acc1, 16); acc1 += __shfl_xor(acc1, 32);
        acc2 += __shfl_xor(acc2, 8); acc2 += __shfl_xor(acc2, 16); acc2 += __shfl_xor(acc2, 32);
        acc3 += __shfl_xor(acc3, 8); acc3 += __shfl_xor(acc3, 16); acc3 += __shfl_xor(acc3, 32);
        if ((l & 56) == 0) {
          float4 rv; rv.x = acc0; rv.y = acc1; rv.z = acc2; rv.w = acc3;
          *(float4*)&red[0][w][rg][0] = rv;
        }
      }
      __syncthreads();
      if (tid >= 256) {
        const int r = tid - 256;
        if (r < 32) {
          const int r2 = r >> 2, jj = r & 3;
          float sum = red[0][0][r2][jj] + red[0][1][r2][jj] +
                      red[0][2][r2][jj] + red[0][3][r2][jj] + lb;
          unsigned long long pv =
              (((unsigned long long)(unsigned)t) << 32) |
              (unsigned long long)__float_as_uint(sum);
          __hip_atomic_store(&Utag[((long)b * Tsz + (t - 1)) * Dsz + base + r],
                             pv, __ATOMIC_RELAXED, __HIP_MEMORY_SCOPE_AGENT);
        }
      }
      __syncthreads();
    }

    // ---- (3) syn/gate + rmsnorm for own 32 rows (j < JCUT) ---------------
    const int j = blk2 & 31;
    if (j < JCUT) {
      const unsigned t_need = (unsigned)(j * 32 + 32);
      const long r0g = (long)b * 1024 + j * 32;   // first M-row

      // converts done? relaxed poll (no buffer_inv), tag-exact
      for (;;) {
        unsigned c0 = __hip_atomic_load(&ConvD[l], __ATOMIC_RELAXED, __HIP_MEMORY_SCOPE_AGENT);
        unsigned c1 = __hip_atomic_load(&ConvD[l + 64], __ATOMIC_RELAXED, __HIP_MEMORY_SCOPE_AGENT);
        if (__all((c0 == MAGICC) & (c1 == MAGICC))) break;
        __builtin_amdgcn_s_sleep(2);
      }
      // scan progress: relaxed poll; pattern + range check rejects garbage
      for (;;) {
        unsigned pk = __hip_atomic_load(&SProg[(b << 5) + (l & 31)],
                                        __ATOMIC_RELAXED, __HIP_MEMORY_SCOPE_AGENT);
        int ok = ((pk >> 12) == (PTAG >> 12)) &
                 ((pk & 0xFFFu) >= t_need) & ((pk & 0xFFFu) <= (unsigned)Tsz);
        if (__all(ok)) break;
        __builtin_amdgcn_s_sleep(2);
      }

      float ssq8[8] = {0.f, 0.f, 0.f, 0.f, 0.f, 0.f, 0.f, 0.f};
      if (tid < 256) {
        // direct-fragment GEMM: out 32 x 1024, K=1024, B-mats {weff, gw}
        const int cw = w * 64;                   // wave col offset in 256-tile
#pragma unroll 1
        for (int bn = 0; bn < 4; ++bn) {
          const int cbase = bn * 256 + cw;
          floatx4_t acc[2][2][4];
#pragma unroll
          for (int mt = 0; mt < 2; ++mt)
#pragma unroll
            for (int m = 0; m < 2; ++m)
#pragma unroll
              for (int n = 0; n < 4; ++n) acc[mt][m][n] = (floatx4_t)(0.f);
          const int fr = (l & 15), fk = (l >> 4) * 8;
#pragma unroll 2
          for (int kc = 0; kc < 32; ++kc) {
            const int ko = kc * 32 + fk;
            short8 af0 = *(const short8*)&Sout[(r0g + fr) * Dsz + ko];
            short8 af1 = *(const short8*)&Sout[(r0g + 16 + fr) * Dsz + ko];
#pragma unroll
            for (int n = 0; n < 4; ++n) {
              const long brow = (long)(cbase + n * 16 + fr) * Dsz + ko;
              short8 bf0 = *(const short8*)&weff_bf[brow];
              short8 bf1 = *(const short8*)&gw_bf[brow];
              acc[0][0][n] = __builtin_amdgcn_mfma_f32_16x16x32_bf16(af0, bf0, acc[0][0][n], 0, 0, 0);
              acc[0][1][n] = __builtin_amdgcn_mfma_f32_16x16x32_bf16(af1, bf0, acc[0][1][n], 0, 0, 0);
              acc[1][0][n] = __builtin_amdgcn_mfma_f32_16x16x32_bf16(af0, bf1, acc[1][0][n], 0, 0, 0);
              acc[1][1][n] = __builtin_amdgcn_mfma_f32_16x16x32_bf16(af1, bf1, acc[1][1][n], 0, 0, 0);
            }
          }
          // epilogue for this bn
#pragma unroll
          for (int m = 0; m < 2; ++m)
#pragma unroll
            for (int n = 0; n < 4; ++n) {
              const int c = cbase + n * 16 + fr;
#pragma unroll
              for (int q = 0; q < 4; ++q) {
                const int r = m * 16 + (l >> 4) * 4 + q;
                const long idx = (r0g + r) * Dsz + c;
                float gsum = acc[1][m][n][q] + gate_b[c];
                float sg = 1.f / (1.f + __expf(-gsum));
                float x2v = x[idx] + acc[0][m][n][q] * sg;
                x2_f[idx] = x2v;
                ssq8[m * 4 + q] += x2v * x2v;
              }
            }
        }
        // reduce ssq over the 16 lanes sharing (l>>4)
#pragma unroll
        for (int i = 0; i < 8; ++i) {
          float v = ssq8[i];
          v += __shfl_xor(v, 1); v += __shfl_xor(v, 2);
          v += __shfl_xor(v, 4); v += __shfl_xor(v, 8);
          ssq8[i] = v;
        }
        if ((l & 15) == 0) {
#pragma unroll
          for (int m = 0; m < 2; ++m)
#pragma unroll
            for (int q = 0; q < 4; ++q)
              ssq_l[w][m * 16 + (l >> 4) * 4 + q] = ssq8[m * 4 + q];
        }
      }
      __syncthreads();   // x2 stores drained; ssq_l visible
      if (tid < 256) {
        const int row = tid >> 3, cg = tid & 7;
        float tot = ssq_l[0][row] + ssq_l[1][row] + ssq_l[2][row] + ssq_l[3][row];
        float scale = 1.0f / sqrtf(tot * (1.0f / Dsz) + 1e-6f);
        const long gr = r0g + row;
#pragma unroll 4
        for (int i = 0; i < 32; ++i) {
          const int c = cg * 128 + i * 4;
          float4 xv = *(const float4*)&x2_f[gr * Dsz + c];
          float4 wv = *(const float4*)&ln2_w[c];
          ushort4 o;
          o.x = f2bf(xv.x * scale * wv.x); o.y = f2bf(xv.y * scale * wv.y);
          o.z = f2bf(xv.z * scale * wv.z); o.w = f2bf(xv.w * scale * wv.w);
          *(ushort4*)&y_bf[gr * Dsz + c] = o;
        }
      }
    }

    // ---- (4) big weight converts (read only by later kernels) ------------
    {
      const long gt = (long)blk2 * 320 + tid, gs = 128 * 320;
      const int n4big = Hsz * Dsz / 4;
      for (long i = gt; i < n4big; i += gs) {
        float4 v = ((const float4*)ffn_wg)[i];
        ushort4 o; o.x = f2bf(v.x); o.y = f2bf(v.y); o.z = f2bf(v.z); o.w = f2bf(v.w);
        ((ushort4*)wg_bf)[i] = o;
        v = ((const float4*)ffn_wu)[i];
        o.x = f2bf(v.x); o.y = f2bf(v.y); o.z = f2bf(v.z); o.w = f2bf(v.w);
        ((ushort4*)wu_bf)[i] = o;
        v = ((const float4*)ffn_wd)[i];
        o.x = f2bf(v.x); o.y = f2bf(v.y); o.z = f2bf(v.z); o.w = f2bf(v.w);
        ((ushort4*)wd_bf)[i] = o;
      }
    }
  }
}

// ---- bf16 MFMA GEMM, C = A @ B^T, m97-style 128x128x32 tile ---------------
// rowStart = (bm/R)*1024 + rowBase + (bm%R)*128  (R=8,rowBase=0 -> bm*128)
// EPI 1: out f32 = aux0 + acc0 * sigmoid(acc1 + aux1[col])
// EPI 2: out bf16 = silu(acc0) * acc1
// EPI 3: out f32 = aux0 + acc0

template<int NB, int EPI>
__global__ __launch_bounds__(256)
void gemm_bt(const unsigned short* __restrict__ A,
             const unsigned short* __restrict__ B0,
             const unsigned short* __restrict__ B1,
             const float* __restrict__ aux0, const float* __restrict__ aux1,
             void* __restrict__ outp, int M, int N, int K,
             int R, int rowBase) {
  __shared__ unsigned short sA[128 * 32];
  __shared__ unsigned short sB[2 * 128 * 32];
  const int tid = threadIdx.x;
  const int w = tid >> 6, l = tid & 63;
  const int wm = w & 1, wn = w >> 1;
  const int bm = blockIdx.x, bn = blockIdx.y;
  const int rowStart = (bm / R) * 1024 + rowBase + (bm % R) * 128;

  floatx4_t acc[NB][4][4];
#pragma unroll
  for (int j = 0; j < NB; ++j)
#pragma unroll
    for (int m = 0; m < 4; ++m)
#pragma unroll
      for (int n = 0; n < 4; ++n) acc[j][m][n] = (floatx4_t)(0.f);

  const int rA = rowStart + 16 * w + (l >> 2);
  const int rB = bn * 128 + 16 * w + (l >> 2);
  const int kl = (l & 3) * 8;
  const unsigned short* gA = A + (long)rA * K + kl;
  const unsigned short* gB0 = B0 + (long)rB * K + kl;
  const unsigned short* gB1 = nullptr;
  if constexpr (NB > 1) gB1 = B1 + (long)rB * K + kl;
  unsigned short* lA = &sA[(16 * w) * 32];
  unsigned short* lB = &sB[(16 * w) * 32];

  for (int k0 = 0; k0 < K; k0 += 32) {
    gll16(gA + k0,              lA);
    gll16(gA + k0 + 64 * K,     lA + 64 * 32);
    gll16(gB0 + k0,             lB);
    gll16(gB0 + k0 + 64 * K,    lB + 64 * 32);
    if constexpr (NB > 1) {
      gll16(gB1 + k0,           lB + 128 * 32);
      gll16(gB1 + k0 + 64 * K,  lB + 192 * 32);
    }
    __syncthreads();
    short8 af[4];
#pragma unroll
    for (int m = 0; m < 4; ++m)
      af[m] = *(const short8*)&sA[(wm * 64 + m * 16 + (l & 15)) * 32 + (l >> 4) * 8];
#pragma unroll
    for (int j = 0; j < NB; ++j) {
#pragma unroll
      for (int n = 0; n < 4; ++n) {
        short8 bf = *(const short8*)&sB[j * 128 * 32 +
                        (wn * 64 + n * 16 + (l & 15)) * 32 + (l >> 4) * 8];
#pragma unroll
        for (int m = 0; m < 4; ++m)
          acc[j][m][n] = __builtin_amdgcn_mfma_f32_16x16x32_bf16(
              af[m], bf, acc[j][m][n], 0, 0, 0);
      }
    }
    __syncthreads();
  }

  const int colBase = bn * 128 + wn * 64;
  const int rowBase2 = rowStart + wm * 64;
#pragma unroll
  for (int m = 0; m < 4; ++m) {
#pragma unroll
    for (int n = 0; n < 4; ++n) {
      const int col = colBase + n * 16 + (l & 15);
#pragma unroll
      for (int j = 0; j < 4; ++j) {
        const int row = rowBase2 + m * 16 + (l >> 4) * 4 + j;
        const long idx = (long)row * N + col;
        float v0 = acc[0][m][n][j];
        if constexpr (EPI == 1) {
          float gsum = acc[NB - 1][m][n][j] + aux1[col];
          float sg = 1.f / (1.f + __expf(-gsum));
          ((float*)outp)[idx] = aux0[idx] + v0 * sg;
        } else if constexpr (EPI == 2) {
          float sil = v0 / (1.f + __expf(-v0));
          ((unsigned short*)outp)[idx] = f2bf(sil * acc[NB - 1][m][n][j]);
        } else {  // EPI == 3
          ((float*)outp)[idx] = aux0[idx] + v0;
        }
      }
    }
  }
}

// ---------------------------------------------------------------------------

extern "C" void kernel_launch(void* const* d_in, const int* in_sizes, int n_in,
                              void* d_out, int out_size, void* d_ws, size_t ws_size,
                              hipStream_t stream) {
  (void)in_sizes; (void)n_in; (void)out_size; (void)ws_size;

  const float* x        = (const float*)d_in[0];
  const float* ln1_w    = (const float*)d_in[1];
  const float* liq_Wi   = (const float*)d_in[2];
  const float* liq_Wr   = (const float*)d_in[3];
  const float* liq_b    = (const float*)d_in[4];
  const float* liq_tau  = (const float*)d_in[5];
  const float* plif_tau = (const float*)d_in[6];
  const float* syn_w    = (const float*)d_in[7];
  const float* gate_w   = (const float*)d_in[8];
  const float* gate_b   = (const float*)d_in[9];
  const float* ln2_w    = (const float*)d_in[10];
  const float* ffn_wg   = (const float*)d_in[11];
  const float* ffn_wu   = (const float*)d_in[12];
  const float* ffn_wd   = (const float*)d_in[13];
  const void*  mask     = d_in[14];

  char* ws = (char*)d_ws;
  const size_t MB = 1024ull * 1024ull;
  unsigned short* wg_bf   = (unsigned short*)(ws + 0 * MB);    // 16 MB
  unsigned short* wu_bf   = (unsigned short*)(ws + 16 * MB);   // 16 MB
  unsigned short* wd_bf   = (unsigned short*)(ws + 32 * MB);   // 16 MB
  unsigned short* weff_bf = (unsigned short*)(ws + 48 * MB);   // 2 MB
  unsigned short* gw_bf   = (unsigned short*)(ws + 50 * MB);   // 2 MB
  float*          x2_f    = (float*)         (ws + 52 * MB);   // 16 MB
  unsigned short* s_bf    = (unsigned short*)(ws + 68 * MB);   // 8 MB
  unsigned short* y_bf    = (unsigned short*)(ws + 76 * MB);   // 8 MB
  unsigned short* ff_bf   = (unsigned short*)(ws + 84 * MB);   // 64 MB (84-148)
  unsigned long long* Utag= (unsigned long long*)(ws + 84 * MB); // 32 MB,
                                    // overlaps ff_bf: Utag dead before FFN
  unsigned long long* hex = (unsigned long long*)(ws + 148 * MB); // 64 KB
  unsigned*       SProg   = (unsigned*)(ws + 148 * MB + 65536);   // 512 B
  unsigned*       ConvD   = (unsigned*)(ws + 148 * MB + 66048);   // 512 B
  float*          out_f   = (float*)d_out;

  const int M = Bsz * Tsz;  // 4096

  // fused: scan (blocks 0-127; self-zeroes Hex/SProg) + producers/workers
  liquid_plif_k<<<256, 320, 0, stream>>>(
      x, ln1_w, liq_Wi, liq_b, liq_Wr, liq_tau, plif_tau, gate_b, ln2_w,
      hex, Utag, s_bf, SProg, ConvD, x2_f, y_bf,
      ffn_wg, wg_bf, ffn_wu, wu_bf, ffn_wd, wd_bf, gate_w, gw_bf,
      syn_w, mask, weff_bf);

  // tail rows [768,1024) per batch: syn/gate + rmsnorm
  gemm_bt<2, 1><<<dim3(8, Dsz / 128), 256, 0, stream>>>(
      s_bf, weff_bf, gw_bf, x, gate_b, x2_f, M, Dsz, Dsz, 2, JCUT * 32);
  rmsnorm_k<<<dim3(256, 4), 256, 0, stream>>>(x2_f, ln2_w, y_bf, JCUT * 32);

  // ff = silu(y@wg^T) * (y@wu^T)  (bf16, full M)
  gemm_bt<2, 2><<<dim3(M / 128, Hsz / 128), 256, 0, stream>>>(
      y_bf, wg_bf, wu_bf, nullptr, nullptr, ff_bf, M, Hsz, Dsz, 8, 0);

  // out = x2 + ff @ wd^T  (f32, full M)
  gemm_bt<1, 3><<<dim3(M / 128, Dsz / 128), 256, 0, stream>>>(
      ff_bf, wd_bf, nullptr, x2_f, nullptr, out_f, M, Dsz, Hsz, 8, 0);
}